// Round 1
// baseline (654.368 us; speedup 1.0000x reference)
//
#include <hip/hip_runtime.h>
#include <hip/hip_bf16.h>
#include <math.h>

#define BB 4
#define NN 4096
#define MM 32
#define FF 64
#define NM (NN*MM)           // 131072 edges per batch
#define NEDGE (BB*NM)        // 524288
#define NNODE (BB*NN)        // 16384
#define AU_SIZE (NNODE*FF)   // 1048576

// ---------------- atom_update ----------------
// wave (64 lanes) per node; lane = feature index
__global__ __launch_bounds__(256) void k_atom(
    const float* __restrict__ atom, const float* __restrict__ bond,
    const int* __restrict__ adj, const float* __restrict__ Wn,
    const float* __restrict__ bn, float* __restrict__ au)
{
  __shared__ float sW[64*64];
  for (int i = threadIdx.x; i < 64*64; i += 256) sW[i] = Wn[i];
  __syncthreads();
  const int lane = threadIdx.x & 63;
  const int nwaves = gridDim.x * 4;
  const float bno = bn[lane];
  for (int node = blockIdx.x*4 + (threadIdx.x>>6); node < NNODE; node += nwaves) {
    const int b = node >> 12;
    const float* bondrow = bond + (size_t)node*(MM*FF);
    const int*  adjrow  = adj  + (size_t)node*MM;
    const float* atomB  = atom + (size_t)b*NN*FF;
    float own  = atom[(size_t)node*FF + lane];
    float root = sqrtf(fabsf(own));               // (x^2)^0.25 == sqrt(|x|)
    float acc = 0.f, wsum = 0.f;
    #pragma unroll 4
    for (int m = 0; m < MM; ++m) {
      float x = bondrow[m*FF + lane];
      float s = x*x;
      #pragma unroll
      for (int off = 32; off; off >>= 1) s += __shfl_xor(s, off);
      float wm = 1.0f / s;                        // (s^0.5)^-2 == 1/s
      int idx = adjrow[m];
      float nb = atomB[(size_t)idx*FF + lane];
      acc  = fmaf(wm, sqrtf(fabsf(nb)), acc);
      wsum += wm;
    }
    // L1 normalization is linear -> divide once at the end
    float pre = root * (acc / fmaxf(wsum, 1e-12f));
    float z = bno;
    #pragma unroll
    for (int f = 0; f < 64; ++f)
      z = fmaf(__shfl(pre, f), sW[f*64 + lane], z);
    au[(size_t)node*FF + lane] = fmaxf(z, 0.f);
  }
}

// ---------------- endpoint histogram ----------------
__global__ __launch_bounds__(256) void k_hist(
    const int* __restrict__ tup, int* __restrict__ cnt)
{
  int i = blockIdx.x*256 + threadIdx.x;
  if (i >= NEDGE) return;
  int b  = i >> 17;                // / NM
  int t0 = tup[(size_t)i*2];
  int t1 = tup[(size_t)i*2 + 1];
  atomicAdd(&cnt[(b<<12) + t0], 1);
  atomicAdd(&cnt[NNODE + (b<<12) + t1], 1);
}

// ---------------- column L1 sums via histogram ----------------
// colsum[b][c] = sum_n cnt[b][n] * au[b][n][c&63]   (au >= 0, so |.| free)
__global__ __launch_bounds__(128) void k_colsum(
    const float* __restrict__ au, const int* __restrict__ cnt,
    float* __restrict__ colsum)
{
  int c  = threadIdx.x;            // 0..127
  int b  = blockIdx.x >> 5;
  int ch = blockIdx.x & 31;
  int f  = c & 63;
  const int*   cp = cnt + ((c >> 6) ? NNODE : 0) + (b<<12);
  const float* ab = au + ((size_t)(b<<12))*64;
  float acc = 0.f;
  int n0 = ch*128;
  for (int n = n0; n < n0+128; ++n)
    acc += (float)cp[n] * ab[(size_t)n*64 + f];
  atomicAdd(&colsum[b*128 + c], acc);
}

// ---------------- P0/P1 precompute ----------------
// P0[n][j] = bias_n2e[j] + sum_c (au[n][c]/colsum[b][c])    * Wn2e[c][j]
// P1[n][j] =              sum_c (au[n][c]/colsum[b][64+c]) * Wn2e[64+c][j]
__global__ __launch_bounds__(256) void k_p01(
    const float* __restrict__ au, const float* __restrict__ colsum,
    const float* __restrict__ Wn2e, const float* __restrict__ bn2e,
    float* __restrict__ P0, float* __restrict__ P1)
{
  __shared__ float sWt[64*64], sWb[64*64];
  for (int i = threadIdx.x; i < 64*64; i += 256) {
    sWt[i] = Wn2e[i];
    sWb[i] = Wn2e[64*64 + i];
  }
  __syncthreads();
  const int lane = threadIdx.x & 63;
  const int nwaves = gridDim.x * 4;
  const float bias = bn2e[lane];
  for (int node = blockIdx.x*4 + (threadIdx.x>>6); node < NNODE; node += nwaves) {
    int b = node >> 12;
    float inv0 = 1.0f / fmaxf(colsum[b*128 + lane],      1e-12f);
    float inv1 = 1.0f / fmaxf(colsum[b*128 + 64 + lane], 1e-12f);
    float a  = au[(size_t)node*64 + lane];
    float x0 = a * inv0, x1 = a * inv1;
    float p0 = bias, p1 = 0.f;
    #pragma unroll
    for (int c = 0; c < 64; ++c) {
      p0 = fmaf(__shfl(x0, c), sWt[c*64 + lane], p0);
      p1 = fmaf(__shfl(x1, c), sWb[c*64 + lane], p1);
    }
    P0[(size_t)node*64 + lane] = p0;
    P1[(size_t)node*64 + lane] = p1;
  }
}

// ---------------- per-edge: tanh + matvec with weight_edge ----------------
__global__ __launch_bounds__(256) void k_edge(
    const float* __restrict__ bond, const int* __restrict__ tup,
    const float* __restrict__ P0, const float* __restrict__ P1,
    const float* __restrict__ We, const float* __restrict__ be,
    float* __restrict__ outB)
{
  __shared__ float sWe[64*64];
  for (int i = threadIdx.x; i < 64*64; i += 256) sWe[i] = We[i];
  __syncthreads();
  const int lane = threadIdx.x & 63;
  const float beo = be[lane];
  const int nwaves = gridDim.x * 4;
  for (int e = blockIdx.x*4 + (threadIdx.x>>6); e < NEDGE; e += nwaves) {
    int b  = e >> 17;
    int t0 = tup[(size_t)e*2];
    int t1 = tup[(size_t)e*2 + 1];
    float p = P0[((size_t)((b<<12) + t0))*64 + lane]
            + P1[((size_t)((b<<12) + t1))*64 + lane];
    float y = tanhf(p);
    float v = bond[(size_t)e*64 + lane] + y;
    float z = beo;
    #pragma unroll
    for (int j = 0; j < 64; ++j)
      z = fmaf(__shfl(v, j), sWe[j*64 + lane], z);
    outB[(size_t)e*64 + lane] = z;
  }
}

extern "C" void kernel_launch(void* const* d_in, const int* in_sizes, int n_in,
                              void* d_out, int out_size, void* d_ws, size_t ws_size,
                              hipStream_t stream)
{
  (void)in_sizes; (void)n_in; (void)out_size; (void)ws_size;
  const float* atom = (const float*)d_in[0];
  const float* bond = (const float*)d_in[1];
  const int*   adj  = (const int*)d_in[2];
  const int*   tup  = (const int*)d_in[3];
  const float* Wn   = (const float*)d_in[4];
  const float* We   = (const float*)d_in[5];
  const float* Wn2e = (const float*)d_in[6];
  const float* bn   = (const float*)d_in[7];
  const float* be   = (const float*)d_in[8];
  const float* bn2e = (const float*)d_in[9];

  float* au   = (float*)d_out;             // output 0: (B,N,64)
  float* outB = (float*)d_out + AU_SIZE;   // output 1: (B,N,M,64)

  char* ws = (char*)d_ws;
  int*   cnt    = (int*)ws;                             // 2*NNODE ints (128 KB)
  float* colsum = (float*)(ws + 2*NNODE*sizeof(int));   // B*128 floats
  float* P0     = (float*)(ws + (size_t)(1<<20));       // 4 MB
  float* P1     = (float*)(ws + (size_t)(5<<20));       // 4 MB

  hipMemsetAsync(d_ws, 0, 2*NNODE*sizeof(int) + BB*128*sizeof(float), stream);

  hipLaunchKernelGGL(k_atom,   dim3(4096),      dim3(256), 0, stream, atom, bond, adj, Wn, bn, au);
  hipLaunchKernelGGL(k_hist,   dim3(NEDGE/256), dim3(256), 0, stream, tup, cnt);
  hipLaunchKernelGGL(k_colsum, dim3(BB*32),     dim3(128), 0, stream, au, cnt, colsum);
  hipLaunchKernelGGL(k_p01,    dim3(2048),      dim3(256), 0, stream, au, colsum, Wn2e, bn2e, P0, P1);
  hipLaunchKernelGGL(k_edge,   dim3(8192),      dim3(256), 0, stream, bond, tup, P0, P1, We, be, outB);
}

// Round 2
// 295.474 us; speedup vs baseline: 2.2146x; 2.2146x over previous
//
#include <hip/hip_runtime.h>
#include <hip/hip_bf16.h>
#include <math.h>

#define BB 4
#define NN 4096
#define MM 32
#define FF 64
#define NM (NN*MM)           // 131072 edges per batch
#define NEDGE (BB*NM)        // 524288
#define NNODE (BB*NN)        // 16384
#define AU_SIZE (NNODE*FF)   // 1048576

typedef __attribute__((ext_vector_type(8))) short bf16x8;
typedef __attribute__((ext_vector_type(4))) float f32x4;

static __device__ __forceinline__ unsigned short f2bf(float x) {
  unsigned int u = __builtin_bit_cast(unsigned int, x);
  unsigned int r = (u + 0x7fffu + ((u >> 16) & 1u)) >> 16;
  return (unsigned short)r;
}
static __device__ __forceinline__ float bf2f(unsigned short h) {
  unsigned int u = ((unsigned int)h) << 16;
  return __builtin_bit_cast(float, u);
}
static __device__ __forceinline__ float tanh_fast(float x) {
  float ex = __expf(2.0f * x);                 // v_exp_f32 path
  return 1.0f - 2.0f * __builtin_amdgcn_rcpf(ex + 1.0f);
}

// ---------------- atom_update ----------------
// wave (64 lanes) per node; lane = feature index
__global__ __launch_bounds__(256) void k_atom(
    const float* __restrict__ atom, const float* __restrict__ bond,
    const int* __restrict__ adj, const float* __restrict__ Wn,
    const float* __restrict__ bn, float* __restrict__ au)
{
  __shared__ float sW[64*64];
  for (int i = threadIdx.x; i < 64*64; i += 256) sW[i] = Wn[i];
  __syncthreads();
  const int lane = threadIdx.x & 63;
  const int nwaves = gridDim.x * 4;
  const float bno = bn[lane];
  for (int node = blockIdx.x*4 + (threadIdx.x>>6); node < NNODE; node += nwaves) {
    const int b = node >> 12;
    const float* bondrow = bond + (size_t)node*(MM*FF);
    const int*  adjrow  = adj  + (size_t)node*MM;
    const float* atomB  = atom + (size_t)b*NN*FF;
    float own  = atom[(size_t)node*FF + lane];
    float root = sqrtf(fabsf(own));               // (x^2)^0.25 == sqrt(|x|)
    float acc = 0.f, wsum = 0.f;
    #pragma unroll 4
    for (int m = 0; m < MM; ++m) {
      float x = bondrow[m*FF + lane];
      float s = x*x;
      #pragma unroll
      for (int off = 32; off; off >>= 1) s += __shfl_xor(s, off);
      float wm = 1.0f / s;                        // (s^0.5)^-2 == 1/s
      int idx = adjrow[m];
      float nb = atomB[(size_t)idx*FF + lane];
      acc  = fmaf(wm, sqrtf(fabsf(nb)), acc);
      wsum += wm;
    }
    float pre = root * (acc / fmaxf(wsum, 1e-12f));
    float z = bno;
    #pragma unroll
    for (int f = 0; f < 64; ++f)
      z = fmaf(__shfl(pre, f), sW[f*64 + lane], z);
    au[(size_t)node*FF + lane] = fmaxf(z, 0.f);
  }
}

// ---------------- endpoint histogram ----------------
__global__ __launch_bounds__(256) void k_hist(
    const int* __restrict__ tup, int* __restrict__ cnt)
{
  int i = blockIdx.x*256 + threadIdx.x;
  if (i >= NEDGE) return;
  int b  = i >> 17;
  int t0 = tup[(size_t)i*2];
  int t1 = tup[(size_t)i*2 + 1];
  atomicAdd(&cnt[(b<<12) + t0], 1);
  atomicAdd(&cnt[NNODE + (b<<12) + t1], 1);
}

// ---------------- column L1 sums via histogram ----------------
__global__ __launch_bounds__(128) void k_colsum(
    const float* __restrict__ au, const int* __restrict__ cnt,
    float* __restrict__ colsum)
{
  int c  = threadIdx.x;            // 0..127
  int b  = blockIdx.x >> 5;
  int ch = blockIdx.x & 31;
  int f  = c & 63;
  const int*   cp = cnt + ((c >> 6) ? NNODE : 0) + (b<<12);
  const float* ab = au + ((size_t)(b<<12))*64;
  float acc = 0.f;
  int n0 = ch*128;
  for (int n = n0; n < n0+128; ++n)
    acc += (float)cp[n] * ab[(size_t)n*64 + f];
  atomicAdd(&colsum[b*128 + c], acc);
}

// ---------------- P0/P1 precompute ----------------
__global__ __launch_bounds__(256) void k_p01(
    const float* __restrict__ au, const float* __restrict__ colsum,
    const float* __restrict__ Wn2e, const float* __restrict__ bn2e,
    float* __restrict__ P0, float* __restrict__ P1)
{
  __shared__ float sWt[64*64], sWb[64*64];
  for (int i = threadIdx.x; i < 64*64; i += 256) {
    sWt[i] = Wn2e[i];
    sWb[i] = Wn2e[64*64 + i];
  }
  __syncthreads();
  const int lane = threadIdx.x & 63;
  const int nwaves = gridDim.x * 4;
  const float bias = bn2e[lane];
  for (int node = blockIdx.x*4 + (threadIdx.x>>6); node < NNODE; node += nwaves) {
    int b = node >> 12;
    float inv0 = 1.0f / fmaxf(colsum[b*128 + lane],      1e-12f);
    float inv1 = 1.0f / fmaxf(colsum[b*128 + 64 + lane], 1e-12f);
    float a  = au[(size_t)node*64 + lane];
    float x0 = a * inv0, x1 = a * inv1;
    float p0 = bias, p1 = 0.f;
    #pragma unroll
    for (int c = 0; c < 64; ++c) {
      p0 = fmaf(__shfl(x0, c), sWt[c*64 + lane], p0);
      p1 = fmaf(__shfl(x1, c), sWb[c*64 + lane], p1);
    }
    P0[(size_t)node*64 + lane] = p0;
    P1[(size_t)node*64 + lane] = p1;
  }
}

// ---------------- per-edge via MFMA ----------------
// Wave handles 16 edges: out[16x64] = v[16x64] @ We[64x64] + be
// v = bond + tanh(P0[t0]+P1[t1]); fp32 recovered via bf16 hi/lo split:
//   AhBh + AlBh + AhBl   (AlBl ~ 2^-18, dropped)
__global__ __launch_bounds__(256) void k_edge_mfma(
    const float* __restrict__ bond, const int* __restrict__ tup,
    const float* __restrict__ P0, const float* __restrict__ P1,
    const float* __restrict__ We, const float* __restrict__ be,
    float* __restrict__ outB)
{
  const int l  = threadIdx.x & 63;
  const int er = l & 15;      // edge-in-tile (M row)
  const int g  = l >> 4;      // k-group

  // preload B fragments: B[k][n], lane l holds col=(l&15), k = kk*32+g*8+j
  bf16x8 wh[4][2], wl[4][2];
  #pragma unroll
  for (int t = 0; t < 4; ++t) {
    const int col = t*16 + er;
    #pragma unroll
    for (int kk = 0; kk < 2; ++kk) {
      #pragma unroll
      for (int j = 0; j < 8; ++j) {
        const int k = kk*32 + g*8 + j;
        float w = We[k*64 + col];
        unsigned short h = f2bf(w);
        wh[t][kk][j] = (short)h;
        wl[t][kk][j] = (short)f2bf(w - bf2f(h));
      }
    }
  }
  float bias[4];
  #pragma unroll
  for (int t = 0; t < 4; ++t) bias[t] = be[t*16 + er];

  const int wid = (blockIdx.x*256 + threadIdx.x) >> 6;
  const int nw  = gridDim.x * 4;
  for (int tile = wid; tile < NEDGE/16; tile += nw) {
    const int e0 = tile*16;
    const int b  = e0 >> 17;
    const int e  = e0 + er;
    int2 tt = *(const int2*)(tup + (size_t)e*2);
    const float* p0r = P0 + ((size_t)((b<<12) + tt.x))*64;
    const float* p1r = P1 + ((size_t)((b<<12) + tt.y))*64;
    const float* br  = bond + (size_t)e*64;

    bf16x8 ah[2], al[2];
    #pragma unroll
    for (int kk = 0; kk < 2; ++kk) {
      const int f0 = kk*32 + g*8;
      float4 b0 = *(const float4*)(br  + f0);
      float4 b1 = *(const float4*)(br  + f0 + 4);
      float4 q0 = *(const float4*)(p0r + f0);
      float4 q1 = *(const float4*)(p0r + f0 + 4);
      float4 r0 = *(const float4*)(p1r + f0);
      float4 r1 = *(const float4*)(p1r + f0 + 4);
      float v[8];
      v[0] = b0.x + tanh_fast(q0.x + r0.x);
      v[1] = b0.y + tanh_fast(q0.y + r0.y);
      v[2] = b0.z + tanh_fast(q0.z + r0.z);
      v[3] = b0.w + tanh_fast(q0.w + r0.w);
      v[4] = b1.x + tanh_fast(q1.x + r1.x);
      v[5] = b1.y + tanh_fast(q1.y + r1.y);
      v[6] = b1.z + tanh_fast(q1.z + r1.z);
      v[7] = b1.w + tanh_fast(q1.w + r1.w);
      #pragma unroll
      for (int j = 0; j < 8; ++j) {
        unsigned short h = f2bf(v[j]);
        ah[kk][j] = (short)h;
        al[kk][j] = (short)f2bf(v[j] - bf2f(h));
      }
    }

    f32x4 acc[4];
    #pragma unroll
    for (int t = 0; t < 4; ++t) {
      acc[t][0] = bias[t]; acc[t][1] = bias[t];
      acc[t][2] = bias[t]; acc[t][3] = bias[t];
    }
    #pragma unroll
    for (int t = 0; t < 4; ++t) {
      acc[t] = __builtin_amdgcn_mfma_f32_16x16x32_bf16(ah[0], wh[t][0], acc[t], 0, 0, 0);
      acc[t] = __builtin_amdgcn_mfma_f32_16x16x32_bf16(ah[1], wh[t][1], acc[t], 0, 0, 0);
      acc[t] = __builtin_amdgcn_mfma_f32_16x16x32_bf16(al[0], wh[t][0], acc[t], 0, 0, 0);
      acc[t] = __builtin_amdgcn_mfma_f32_16x16x32_bf16(al[1], wh[t][1], acc[t], 0, 0, 0);
      acc[t] = __builtin_amdgcn_mfma_f32_16x16x32_bf16(ah[0], wl[t][0], acc[t], 0, 0, 0);
      acc[t] = __builtin_amdgcn_mfma_f32_16x16x32_bf16(ah[1], wl[t][1], acc[t], 0, 0, 0);
    }

    // D layout: row = g*4 + r (edge), col = t*16 + er
    float* orow = outB + (size_t)e0*64;
    #pragma unroll
    for (int t = 0; t < 4; ++t)
      #pragma unroll
      for (int r = 0; r < 4; ++r)
        orow[(size_t)(g*4 + r)*64 + t*16 + er] = acc[t][r];
  }
}

extern "C" void kernel_launch(void* const* d_in, const int* in_sizes, int n_in,
                              void* d_out, int out_size, void* d_ws, size_t ws_size,
                              hipStream_t stream)
{
  (void)in_sizes; (void)n_in; (void)out_size; (void)ws_size;
  const float* atom = (const float*)d_in[0];
  const float* bond = (const float*)d_in[1];
  const int*   adj  = (const int*)d_in[2];
  const int*   tup  = (const int*)d_in[3];
  const float* Wn   = (const float*)d_in[4];
  const float* We   = (const float*)d_in[5];
  const float* Wn2e = (const float*)d_in[6];
  const float* bn   = (const float*)d_in[7];
  const float* be   = (const float*)d_in[8];
  const float* bn2e = (const float*)d_in[9];

  float* au   = (float*)d_out;             // output 0: (B,N,64)
  float* outB = (float*)d_out + AU_SIZE;   // output 1: (B,N,M,64)

  char* ws = (char*)d_ws;
  int*   cnt    = (int*)ws;                             // 2*NNODE ints
  float* colsum = (float*)(ws + 2*NNODE*sizeof(int));   // B*128 floats
  float* P0     = (float*)(ws + (size_t)(1<<20));       // 4 MB
  float* P1     = (float*)(ws + (size_t)(5<<20));       // 4 MB

  hipMemsetAsync(d_ws, 0, 2*NNODE*sizeof(int) + BB*128*sizeof(float), stream);

  hipLaunchKernelGGL(k_atom,      dim3(4096),      dim3(256), 0, stream, atom, bond, adj, Wn, bn, au);
  hipLaunchKernelGGL(k_hist,      dim3(NEDGE/256), dim3(256), 0, stream, tup, cnt);
  hipLaunchKernelGGL(k_colsum,    dim3(BB*32),     dim3(128), 0, stream, au, cnt, colsum);
  hipLaunchKernelGGL(k_p01,       dim3(2048),      dim3(256), 0, stream, au, colsum, Wn2e, bn2e, P0, P1);
  hipLaunchKernelGGL(k_edge_mfma, dim3(2048),      dim3(256), 0, stream, bond, tup, P0, P1, We, be, outB);
}

// Round 4
// 180.312 us; speedup vs baseline: 3.6291x; 1.6387x over previous
//
#include <hip/hip_runtime.h>
#include <hip/hip_bf16.h>
#include <math.h>

#define BB 4
#define NN 4096
#define MM 32
#define FF 64
#define NM (NN*MM)           // 131072 edges per batch
#define NEDGE (BB*NM)        // 524288
#define NNODE (BB*NN)        // 16384
#define AU_SIZE (NNODE*FF)   // 1048576

typedef __attribute__((ext_vector_type(8))) short bf16x8;
typedef __attribute__((ext_vector_type(4))) float f32x4;

static __device__ __forceinline__ unsigned short f2bf(float x) {
  unsigned int u = __builtin_bit_cast(unsigned int, x);
  unsigned int r = (u + 0x7fffu + ((u >> 16) & 1u)) >> 16;
  return (unsigned short)r;
}
static __device__ __forceinline__ float bf2f(unsigned short h) {
  unsigned int u = ((unsigned int)h) << 16;
  return __builtin_bit_cast(float, u);
}
static __device__ __forceinline__ float tanh_fast(float x) {
  float ex = __expf(2.0f * x);
  return 1.0f - 2.0f * __builtin_amdgcn_rcpf(ex + 1.0f);
}

// ---------------- ar = sqrt(|atom|) ----------------
__global__ __launch_bounds__(256) void k_root(
    const float* __restrict__ atom, float* __restrict__ ar)
{
  int i = blockIdx.x*256 + threadIdx.x;     // over AU_SIZE/4 float4s
  float4 v = ((const float4*)atom)[i];
  float4 r;
  r.x = sqrtf(fabsf(v.x)); r.y = sqrtf(fabsf(v.y));
  r.z = sqrtf(fabsf(v.z)); r.w = sqrtf(fabsf(v.w));
  ((float4*)ar)[i] = r;
}

// ---------------- pre = root * (Sum wm*ar[idx]) / Sum wm ----------------
// wave per node. Phase 1: lane=(m, f-half) computes bond sq-sums with ONE
// shfl_xor. Phase 2: lane=f, gather-FMA with readlane-broadcast idx/weight.
// NOTE: lane l holds adj element (l&31)  -> broadcast idx from lane m.
//       lane 2m holds wm for neighbor m  -> broadcast weight from lane 2m.
__global__ __launch_bounds__(256) void k_pre(
    const float* __restrict__ ar, const float* __restrict__ bond,
    const int* __restrict__ adj, float* __restrict__ pre)
{
  const int lane = threadIdx.x & 63;
  const int nwaves = gridDim.x * 4;
  for (int node = blockIdx.x*4 + (threadIdx.x>>6); node < NNODE; node += nwaves) {
    const int b = node >> 12;
    const float* bondrow = bond + (size_t)node*(MM*FF);
    // phase 1: lane covers m = lane>>1, f in [ (lane&1)*32, +32 )
    const int base = (lane>>1)*FF + (lane&1)*32;
    float s = 0.f;
    #pragma unroll
    for (int i = 0; i < 8; ++i) {
      float4 v = *(const float4*)(bondrow + base + i*4);
      s = fmaf(v.x, v.x, s); s = fmaf(v.y, v.y, s);
      s = fmaf(v.z, v.z, s); s = fmaf(v.w, v.w, s);
    }
    s += __shfl_xor(s, 1);                  // full 64-f sum for m=lane>>1
    float wm = 1.0f / s;                    // (s^0.5)^-2
    float wsum = wm;
    #pragma unroll
    for (int off = 2; off <= 32; off <<= 1) wsum += __shfl_xor(wsum, off);

    // phase 2: lane = f
    int idxv = adj[(size_t)node*MM + (lane & 31)];
    const float* arB = ar + (size_t)b*NN*FF;
    float acc = 0.f;
    #pragma unroll 8
    for (int m = 0; m < MM; ++m) {
      int idx = __builtin_amdgcn_readlane(idxv, m);          // adj[m] (lane m)
      float w = __builtin_bit_cast(float,
                  __builtin_amdgcn_readlane(__builtin_bit_cast(int, wm), 2*m)); // wm[m] (lane 2m)
      acc = fmaf(w, arB[(size_t)idx*FF + lane], acc);
    }
    float own = ar[(size_t)node*FF + lane];
    pre[(size_t)node*FF + lane] = own * acc / fmaxf(wsum, 1e-12f);
  }
}

// ---------------- au = relu(pre @ Wn + bn), MFMA, 16 nodes/wave ----------------
__global__ __launch_bounds__(256) void k_au(
    const float* __restrict__ pre, const float* __restrict__ Wn,
    const float* __restrict__ bn, float* __restrict__ au)
{
  const int l  = threadIdx.x & 63;
  const int er = l & 15;
  const int g  = l >> 4;
  bf16x8 wh[4][2], wl[4][2];
  #pragma unroll
  for (int t = 0; t < 4; ++t) {
    const int col = t*16 + er;
    #pragma unroll
    for (int kk = 0; kk < 2; ++kk)
      #pragma unroll
      for (int j = 0; j < 8; ++j) {
        const int k = kk*32 + g*8 + j;
        float w = Wn[k*64 + col];
        unsigned short h = f2bf(w);
        wh[t][kk][j] = (short)h;
        wl[t][kk][j] = (short)f2bf(w - bf2f(h));
      }
  }
  float bias[4];
  #pragma unroll
  for (int t = 0; t < 4; ++t) bias[t] = bn[t*16 + er];

  const int wid = (blockIdx.x*256 + threadIdx.x) >> 6;
  const int nw  = gridDim.x * 4;
  for (int tile = wid; tile < NNODE/16; tile += nw) {
    const int n0 = tile*16;
    const float* pr = pre + (size_t)(n0 + er)*64;
    bf16x8 ah[2], al[2];
    #pragma unroll
    for (int kk = 0; kk < 2; ++kk) {
      const int f0 = kk*32 + g*8;
      float4 a0 = *(const float4*)(pr + f0);
      float4 a1 = *(const float4*)(pr + f0 + 4);
      float v[8] = {a0.x,a0.y,a0.z,a0.w,a1.x,a1.y,a1.z,a1.w};
      #pragma unroll
      for (int j = 0; j < 8; ++j) {
        unsigned short h = f2bf(v[j]);
        ah[kk][j] = (short)h;
        al[kk][j] = (short)f2bf(v[j] - bf2f(h));
      }
    }
    f32x4 acc[4];
    #pragma unroll
    for (int t = 0; t < 4; ++t) {
      acc[t][0]=bias[t]; acc[t][1]=bias[t]; acc[t][2]=bias[t]; acc[t][3]=bias[t];
      acc[t] = __builtin_amdgcn_mfma_f32_16x16x32_bf16(ah[0], wh[t][0], acc[t], 0,0,0);
      acc[t] = __builtin_amdgcn_mfma_f32_16x16x32_bf16(ah[1], wh[t][1], acc[t], 0,0,0);
      acc[t] = __builtin_amdgcn_mfma_f32_16x16x32_bf16(al[0], wh[t][0], acc[t], 0,0,0);
      acc[t] = __builtin_amdgcn_mfma_f32_16x16x32_bf16(al[1], wh[t][1], acc[t], 0,0,0);
      acc[t] = __builtin_amdgcn_mfma_f32_16x16x32_bf16(ah[0], wl[t][0], acc[t], 0,0,0);
      acc[t] = __builtin_amdgcn_mfma_f32_16x16x32_bf16(ah[1], wl[t][1], acc[t], 0,0,0);
    }
    #pragma unroll
    for (int t = 0; t < 4; ++t)
      #pragma unroll
      for (int r = 0; r < 4; ++r)
        au[(size_t)(n0 + g*4 + r)*64 + t*16 + er] = fmaxf(acc[t][r], 0.f);
  }
}

// ---------------- endpoint histogram ----------------
__global__ __launch_bounds__(256) void k_hist(
    const int* __restrict__ tup, int* __restrict__ cnt)
{
  int i = blockIdx.x*256 + threadIdx.x;
  if (i >= NEDGE) return;
  int b  = i >> 17;
  int t0 = tup[(size_t)i*2];
  int t1 = tup[(size_t)i*2 + 1];
  atomicAdd(&cnt[(b<<12) + t0], 1);
  atomicAdd(&cnt[NNODE + (b<<12) + t1], 1);
}

// ---------------- column L1 sums via histogram ----------------
__global__ __launch_bounds__(128) void k_colsum(
    const float* __restrict__ au, const int* __restrict__ cnt,
    float* __restrict__ colsum)
{
  int c  = threadIdx.x;            // 0..127
  int b  = blockIdx.x >> 5;
  int ch = blockIdx.x & 31;
  int f  = c & 63;
  const int*   cp = cnt + ((c >> 6) ? NNODE : 0) + (b<<12);
  const float* ab = au + ((size_t)(b<<12))*64;
  float acc = 0.f;
  int n0 = ch*128;
  for (int n = n0; n < n0+128; ++n)
    acc += (float)cp[n] * ab[(size_t)n*64 + f];
  atomicAdd(&colsum[b*128 + c], acc);
}

// ---------------- P0/P1 via MFMA (single bf16 term; matvec is O(1e-3)) ----------------
__global__ __launch_bounds__(256) void k_p01(
    const float* __restrict__ au, const float* __restrict__ colsum,
    const float* __restrict__ Wn2e, const float* __restrict__ bn2e,
    float* __restrict__ P0, float* __restrict__ P1)
{
  const int l  = threadIdx.x & 63;
  const int er = l & 15;
  const int g  = l >> 4;
  bf16x8 wt[4][2], wb[4][2];
  #pragma unroll
  for (int t = 0; t < 4; ++t) {
    const int col = t*16 + er;
    #pragma unroll
    for (int kk = 0; kk < 2; ++kk)
      #pragma unroll
      for (int j = 0; j < 8; ++j) {
        const int k = kk*32 + g*8 + j;
        wt[t][kk][j] = (short)f2bf(Wn2e[k*64 + col]);
        wb[t][kk][j] = (short)f2bf(Wn2e[(64 + k)*64 + col]);
      }
  }
  float bias[4];
  #pragma unroll
  for (int t = 0; t < 4; ++t) bias[t] = bn2e[t*16 + er];

  const int wid = (blockIdx.x*256 + threadIdx.x) >> 6;
  const int nw  = gridDim.x * 4;
  for (int tile = wid; tile < NNODE/16; tile += nw) {
    const int n0 = tile*16;
    const int b  = tile >> 8;
    const float* ar_ = au + (size_t)(n0 + er)*64;
    bf16x8 x0[2], x1[2];
    #pragma unroll
    for (int kk = 0; kk < 2; ++kk) {
      const int f0 = kk*32 + g*8;
      float4 a0 = *(const float4*)(ar_ + f0);
      float4 a1 = *(const float4*)(ar_ + f0 + 4);
      float4 c0 = *(const float4*)(colsum + b*128 + f0);
      float4 c1 = *(const float4*)(colsum + b*128 + f0 + 4);
      float4 d0 = *(const float4*)(colsum + b*128 + 64 + f0);
      float4 d1 = *(const float4*)(colsum + b*128 + 64 + f0 + 4);
      float v[8] = {a0.x,a0.y,a0.z,a0.w,a1.x,a1.y,a1.z,a1.w};
      float c[8] = {c0.x,c0.y,c0.z,c0.w,c1.x,c1.y,c1.z,c1.w};
      float d[8] = {d0.x,d0.y,d0.z,d0.w,d1.x,d1.y,d1.z,d1.w};
      #pragma unroll
      for (int j = 0; j < 8; ++j) {
        x0[kk][j] = (short)f2bf(v[j] * __builtin_amdgcn_rcpf(fmaxf(c[j], 1e-12f)));
        x1[kk][j] = (short)f2bf(v[j] * __builtin_amdgcn_rcpf(fmaxf(d[j], 1e-12f)));
      }
    }
    f32x4 p0[4], p1[4];
    #pragma unroll
    for (int t = 0; t < 4; ++t) {
      p0[t][0]=bias[t]; p0[t][1]=bias[t]; p0[t][2]=bias[t]; p0[t][3]=bias[t];
      p1[t][0]=0.f; p1[t][1]=0.f; p1[t][2]=0.f; p1[t][3]=0.f;
      p0[t] = __builtin_amdgcn_mfma_f32_16x16x32_bf16(x0[0], wt[t][0], p0[t], 0,0,0);
      p0[t] = __builtin_amdgcn_mfma_f32_16x16x32_bf16(x0[1], wt[t][1], p0[t], 0,0,0);
      p1[t] = __builtin_amdgcn_mfma_f32_16x16x32_bf16(x1[0], wb[t][0], p1[t], 0,0,0);
      p1[t] = __builtin_amdgcn_mfma_f32_16x16x32_bf16(x1[1], wb[t][1], p1[t], 0,0,0);
    }
    #pragma unroll
    for (int t = 0; t < 4; ++t)
      #pragma unroll
      for (int r = 0; r < 4; ++r) {
        P0[(size_t)(n0 + g*4 + r)*64 + t*16 + er] = p0[t][r];
        P1[(size_t)(n0 + g*4 + r)*64 + t*16 + er] = p1[t][r];
      }
  }
}

// ---------------- per-edge via MFMA ----------------
__global__ __launch_bounds__(256) void k_edge_mfma(
    const float* __restrict__ bond, const int* __restrict__ tup,
    const float* __restrict__ P0, const float* __restrict__ P1,
    const float* __restrict__ We, const float* __restrict__ be,
    float* __restrict__ outB)
{
  const int l  = threadIdx.x & 63;
  const int er = l & 15;
  const int g  = l >> 4;
  bf16x8 wh[4][2], wl[4][2];
  #pragma unroll
  for (int t = 0; t < 4; ++t) {
    const int col = t*16 + er;
    #pragma unroll
    for (int kk = 0; kk < 2; ++kk)
      #pragma unroll
      for (int j = 0; j < 8; ++j) {
        const int k = kk*32 + g*8 + j;
        float w = We[k*64 + col];
        unsigned short h = f2bf(w);
        wh[t][kk][j] = (short)h;
        wl[t][kk][j] = (short)f2bf(w - bf2f(h));
      }
  }
  float bias[4];
  #pragma unroll
  for (int t = 0; t < 4; ++t) bias[t] = be[t*16 + er];

  const int wid = (blockIdx.x*256 + threadIdx.x) >> 6;
  const int nw  = gridDim.x * 4;
  for (int tile = wid; tile < NEDGE/16; tile += nw) {
    const int e0 = tile*16;
    const int b  = e0 >> 17;
    const int e  = e0 + er;
    int2 tt = *(const int2*)(tup + (size_t)e*2);
    const float* p0r = P0 + ((size_t)((b<<12) + tt.x))*64;
    const float* p1r = P1 + ((size_t)((b<<12) + tt.y))*64;
    const float* br  = bond + (size_t)e*64;

    bf16x8 ah[2], al[2];
    #pragma unroll
    for (int kk = 0; kk < 2; ++kk) {
      const int f0 = kk*32 + g*8;
      float4 b0 = *(const float4*)(br  + f0);
      float4 b1 = *(const float4*)(br  + f0 + 4);
      float4 q0 = *(const float4*)(p0r + f0);
      float4 q1 = *(const float4*)(p0r + f0 + 4);
      float4 r0 = *(const float4*)(p1r + f0);
      float4 r1 = *(const float4*)(p1r + f0 + 4);
      float v[8];
      v[0] = b0.x + tanh_fast(q0.x + r0.x);
      v[1] = b0.y + tanh_fast(q0.y + r0.y);
      v[2] = b0.z + tanh_fast(q0.z + r0.z);
      v[3] = b0.w + tanh_fast(q0.w + r0.w);
      v[4] = b1.x + tanh_fast(q1.x + r1.x);
      v[5] = b1.y + tanh_fast(q1.y + r1.y);
      v[6] = b1.z + tanh_fast(q1.z + r1.z);
      v[7] = b1.w + tanh_fast(q1.w + r1.w);
      #pragma unroll
      for (int j = 0; j < 8; ++j) {
        unsigned short h = f2bf(v[j]);
        ah[kk][j] = (short)h;
        al[kk][j] = (short)f2bf(v[j] - bf2f(h));
      }
    }

    f32x4 acc[4];
    #pragma unroll
    for (int t = 0; t < 4; ++t) {
      acc[t][0]=bias[t]; acc[t][1]=bias[t]; acc[t][2]=bias[t]; acc[t][3]=bias[t];
      acc[t] = __builtin_amdgcn_mfma_f32_16x16x32_bf16(ah[0], wh[t][0], acc[t], 0,0,0);
      acc[t] = __builtin_amdgcn_mfma_f32_16x16x32_bf16(ah[1], wh[t][1], acc[t], 0,0,0);
      acc[t] = __builtin_amdgcn_mfma_f32_16x16x32_bf16(al[0], wh[t][0], acc[t], 0,0,0);
      acc[t] = __builtin_amdgcn_mfma_f32_16x16x32_bf16(al[1], wh[t][1], acc[t], 0,0,0);
      acc[t] = __builtin_amdgcn_mfma_f32_16x16x32_bf16(ah[0], wl[t][0], acc[t], 0,0,0);
      acc[t] = __builtin_amdgcn_mfma_f32_16x16x32_bf16(ah[1], wl[t][1], acc[t], 0,0,0);
    }

    float* orow = outB + (size_t)e0*64;
    #pragma unroll
    for (int t = 0; t < 4; ++t)
      #pragma unroll
      for (int r = 0; r < 4; ++r)
        orow[(size_t)(g*4 + r)*64 + t*16 + er] = acc[t][r];
  }
}

extern "C" void kernel_launch(void* const* d_in, const int* in_sizes, int n_in,
                              void* d_out, int out_size, void* d_ws, size_t ws_size,
                              hipStream_t stream)
{
  (void)in_sizes; (void)n_in; (void)out_size; (void)ws_size;
  const float* atom = (const float*)d_in[0];
  const float* bond = (const float*)d_in[1];
  const int*   adj  = (const int*)d_in[2];
  const int*   tup  = (const int*)d_in[3];
  const float* Wn   = (const float*)d_in[4];
  const float* We   = (const float*)d_in[5];
  const float* Wn2e = (const float*)d_in[6];
  const float* bn   = (const float*)d_in[7];
  const float* be   = (const float*)d_in[8];
  const float* bn2e = (const float*)d_in[9];

  float* au   = (float*)d_out;             // output 0: (B,N,64)
  float* outB = (float*)d_out + AU_SIZE;   // output 1: (B,N,M,64)

  char* ws = (char*)d_ws;
  int*   cnt    = (int*)ws;                             // 128 KB
  float* colsum = (float*)(ws + 2*NNODE*sizeof(int));   // 2 KB
  float* ar     = (float*)(ws + (size_t)(1<<20));       // 4 MB (dead after k_pre)
  float* pre    = (float*)(ws + (size_t)(6<<20));       // 4 MB (dead after k_au)
  float* P0     = (float*)(ws + (size_t)(6<<20));       // aliases pre (safe: serial stream)
  float* P1     = (float*)(ws + (size_t)(1<<20));       // aliases ar  (safe: serial stream)

  hipMemsetAsync(d_ws, 0, 2*NNODE*sizeof(int) + BB*128*sizeof(float), stream);

  hipLaunchKernelGGL(k_root,      dim3(AU_SIZE/4/256), dim3(256), 0, stream, atom, ar);
  hipLaunchKernelGGL(k_pre,       dim3(4096),          dim3(256), 0, stream, ar, bond, adj, pre);
  hipLaunchKernelGGL(k_au,        dim3(256),           dim3(256), 0, stream, pre, Wn, bn, au);
  hipLaunchKernelGGL(k_hist,      dim3(NEDGE/256),     dim3(256), 0, stream, tup, cnt);
  hipLaunchKernelGGL(k_colsum,    dim3(BB*32),         dim3(128), 0, stream, au, cnt, colsum);
  hipLaunchKernelGGL(k_p01,       dim3(256),           dim3(256), 0, stream, au, colsum, Wn2e, bn2e, P0, P1);
  hipLaunchKernelGGL(k_edge_mfma, dim3(2048),          dim3(256), 0, stream, bond, tup, P0, P1, We, be, outB);
}

// Round 5
// 170.852 us; speedup vs baseline: 3.8300x; 1.0554x over previous
//
#include <hip/hip_runtime.h>
#include <hip/hip_bf16.h>
#include <math.h>

#define BB 4
#define NN 4096
#define MM 32
#define FF 64
#define NM (NN*MM)           // 131072 edges per batch
#define NEDGE (BB*NM)        // 524288
#define NNODE (BB*NN)        // 16384
#define AU_SIZE (NNODE*FF)   // 1048576

typedef __attribute__((ext_vector_type(8))) short bf16x8;
typedef __attribute__((ext_vector_type(4))) float f32x4;

static __device__ __forceinline__ unsigned short f2bf(float x) {
  unsigned int u = __builtin_bit_cast(unsigned int, x);
  unsigned int r = (u + 0x7fffu + ((u >> 16) & 1u)) >> 16;
  return (unsigned short)r;
}
static __device__ __forceinline__ float bf2f(unsigned short h) {
  unsigned int u = ((unsigned int)h) << 16;
  return __builtin_bit_cast(float, u);
}
static __device__ __forceinline__ float tanh_fast(float x) {
  float ex = __expf(2.0f * x);
  return 1.0f - 2.0f * __builtin_amdgcn_rcpf(ex + 1.0f);
}
static __device__ __forceinline__ float readlane_f(float v, int lane) {
  return __builtin_bit_cast(float,
           __builtin_amdgcn_readlane(__builtin_bit_cast(int, v), lane));
}

// ---------------- ar = sqrt(|atom|) ----------------
__global__ __launch_bounds__(256) void k_root(
    const float* __restrict__ atom, float* __restrict__ ar)
{
  int i = blockIdx.x*256 + threadIdx.x;
  float4 v = ((const float4*)atom)[i];
  float4 r;
  r.x = sqrtf(fabsf(v.x)); r.y = sqrtf(fabsf(v.y));
  r.z = sqrtf(fabsf(v.z)); r.w = sqrtf(fabsf(v.w));
  ((float4*)ar)[i] = r;
}

// ---------------- pre = root * (Sum wm*ar[idx]) / Sum wm ----------------
// wave per node, XCD-pinned per batch. Phase 1: fully-coalesced f4 reads
// (f4 j = i*64+lane, owner m = i*4 + (lane>>4)); 16-lane butterflies give
// per-m sums; cross-group butterfly gives wsum. Phase 2: readlane-broadcast
// gather (idx from lane m, weight inv[m>>2] from lane (m&3)*16).
__global__ __launch_bounds__(256) void k_pre(
    const float* __restrict__ ar, const float* __restrict__ bond,
    const int* __restrict__ adj, float* __restrict__ pre)
{
  const int lane = threadIdx.x & 63;
  // XCD swizzle: blockIdx round-robins 8 XCDs; pin batch b to XCD pair {2b,2b+1}
  const int b      = (blockIdx.x & 7) >> 1;
  const int within = ((blockIdx.x & 1) << 9) + (blockIdx.x >> 3);   // [0,1024)
  const int node   = (b << 12) + within*4 + (threadIdx.x >> 6);

  const float4* brow4 = (const float4*)(bond + (size_t)node*(MM*FF));
  float s[8];
  #pragma unroll
  for (int i = 0; i < 8; ++i) {
    float4 v = brow4[i*64 + lane];
    s[i] = fmaf(v.x, v.x, fmaf(v.y, v.y, fmaf(v.z, v.z, v.w*v.w)));
  }
  #pragma unroll
  for (int i = 0; i < 8; ++i) {
    #pragma unroll
    for (int off = 1; off <= 8; off <<= 1) s[i] += __shfl_xor(s[i], off);
  }
  float inv[8];
  float wsum = 0.f;
  #pragma unroll
  for (int i = 0; i < 8; ++i) { inv[i] = 1.0f / s[i]; wsum += inv[i]; }
  wsum += __shfl_xor(wsum, 16);
  wsum += __shfl_xor(wsum, 32);

  int idxv = adj[(size_t)node*MM + (lane & 31)];
  const float* arB = ar + (size_t)b*NN*FF;
  float acc = 0.f;
  #pragma unroll
  for (int m = 0; m < MM; ++m) {
    int   idx = __builtin_amdgcn_readlane(idxv, m);       // adj[m] from lane m
    float w   = readlane_f(inv[m >> 2], (m & 3)*16);      // wm from group (m&3)
    acc = fmaf(w, arB[(size_t)idx*FF + lane], acc);
  }
  float own = ar[(size_t)node*FF + lane];
  pre[(size_t)node*FF + lane] = own * acc / fmaxf(wsum, 1e-12f);
}

// ---------------- au = relu(pre @ Wn + bn), MFMA, 16 nodes/wave ----------------
__global__ __launch_bounds__(256) void k_au(
    const float* __restrict__ pre, const float* __restrict__ Wn,
    const float* __restrict__ bn, float* __restrict__ au)
{
  const int l  = threadIdx.x & 63;
  const int er = l & 15;
  const int g  = l >> 4;
  bf16x8 wh[4][2], wl[4][2];
  #pragma unroll
  for (int t = 0; t < 4; ++t) {
    const int col = t*16 + er;
    #pragma unroll
    for (int kk = 0; kk < 2; ++kk)
      #pragma unroll
      for (int j = 0; j < 8; ++j) {
        const int k = kk*32 + g*8 + j;
        float w = Wn[k*64 + col];
        unsigned short h = f2bf(w);
        wh[t][kk][j] = (short)h;
        wl[t][kk][j] = (short)f2bf(w - bf2f(h));
      }
  }
  float bias[4];
  #pragma unroll
  for (int t = 0; t < 4; ++t) bias[t] = bn[t*16 + er];

  const int wid = (blockIdx.x*256 + threadIdx.x) >> 6;
  const int nw  = gridDim.x * 4;
  for (int tile = wid; tile < NNODE/16; tile += nw) {
    const int n0 = tile*16;
    const float* pr = pre + (size_t)(n0 + er)*64;
    bf16x8 ah[2], al[2];
    #pragma unroll
    for (int kk = 0; kk < 2; ++kk) {
      const int f0 = kk*32 + g*8;
      float4 a0 = *(const float4*)(pr + f0);
      float4 a1 = *(const float4*)(pr + f0 + 4);
      float v[8] = {a0.x,a0.y,a0.z,a0.w,a1.x,a1.y,a1.z,a1.w};
      #pragma unroll
      for (int j = 0; j < 8; ++j) {
        unsigned short h = f2bf(v[j]);
        ah[kk][j] = (short)h;
        al[kk][j] = (short)f2bf(v[j] - bf2f(h));
      }
    }
    f32x4 acc[4];
    #pragma unroll
    for (int t = 0; t < 4; ++t) {
      acc[t][0]=bias[t]; acc[t][1]=bias[t]; acc[t][2]=bias[t]; acc[t][3]=bias[t];
      acc[t] = __builtin_amdgcn_mfma_f32_16x16x32_bf16(ah[0], wh[t][0], acc[t], 0,0,0);
      acc[t] = __builtin_amdgcn_mfma_f32_16x16x32_bf16(ah[1], wh[t][1], acc[t], 0,0,0);
      acc[t] = __builtin_amdgcn_mfma_f32_16x16x32_bf16(al[0], wh[t][0], acc[t], 0,0,0);
      acc[t] = __builtin_amdgcn_mfma_f32_16x16x32_bf16(al[1], wh[t][1], acc[t], 0,0,0);
      acc[t] = __builtin_amdgcn_mfma_f32_16x16x32_bf16(ah[0], wl[t][0], acc[t], 0,0,0);
      acc[t] = __builtin_amdgcn_mfma_f32_16x16x32_bf16(ah[1], wl[t][1], acc[t], 0,0,0);
    }
    #pragma unroll
    for (int t = 0; t < 4; ++t)
      #pragma unroll
      for (int r = 0; r < 4; ++r)
        au[(size_t)(n0 + g*4 + r)*64 + t*16 + er] = fmaxf(acc[t][r], 0.f);
  }
}

// ---------------- endpoint histogram ----------------
__global__ __launch_bounds__(256) void k_hist(
    const int* __restrict__ tup, int* __restrict__ cnt)
{
  int i = blockIdx.x*256 + threadIdx.x;
  if (i >= NEDGE) return;
  int b  = i >> 17;
  int t0 = tup[(size_t)i*2];
  int t1 = tup[(size_t)i*2 + 1];
  atomicAdd(&cnt[(b<<12) + t0], 1);
  atomicAdd(&cnt[NNODE + (b<<12) + t1], 1);
}

// ---------------- column L1 sums via histogram ----------------
__global__ __launch_bounds__(128) void k_colsum(
    const float* __restrict__ au, const int* __restrict__ cnt,
    float* __restrict__ colsum)
{
  int c  = threadIdx.x;            // 0..127
  int b  = blockIdx.x >> 5;
  int ch = blockIdx.x & 31;
  int f  = c & 63;
  const int*   cp = cnt + ((c >> 6) ? NNODE : 0) + (b<<12);
  const float* ab = au + ((size_t)(b<<12))*64;
  float acc = 0.f;
  int n0 = ch*128;
  for (int n = n0; n < n0+128; ++n)
    acc += (float)cp[n] * ab[(size_t)n*64 + f];
  atomicAdd(&colsum[b*128 + c], acc);
}

// ---------------- P0/P1 via MFMA (single bf16 term; matvec is O(1e-3)) ----------------
__global__ __launch_bounds__(256) void k_p01(
    const float* __restrict__ au, const float* __restrict__ colsum,
    const float* __restrict__ Wn2e, const float* __restrict__ bn2e,
    float* __restrict__ P0, float* __restrict__ P1)
{
  const int l  = threadIdx.x & 63;
  const int er = l & 15;
  const int g  = l >> 4;
  bf16x8 wt[4][2], wb[4][2];
  #pragma unroll
  for (int t = 0; t < 4; ++t) {
    const int col = t*16 + er;
    #pragma unroll
    for (int kk = 0; kk < 2; ++kk)
      #pragma unroll
      for (int j = 0; j < 8; ++j) {
        const int k = kk*32 + g*8 + j;
        wt[t][kk][j] = (short)f2bf(Wn2e[k*64 + col]);
        wb[t][kk][j] = (short)f2bf(Wn2e[(64 + k)*64 + col]);
      }
  }
  float bias[4];
  #pragma unroll
  for (int t = 0; t < 4; ++t) bias[t] = bn2e[t*16 + er];

  const int wid = (blockIdx.x*256 + threadIdx.x) >> 6;
  const int nw  = gridDim.x * 4;
  for (int tile = wid; tile < NNODE/16; tile += nw) {
    const int n0 = tile*16;
    const int b  = tile >> 8;
    const float* ar_ = au + (size_t)(n0 + er)*64;
    bf16x8 x0[2], x1[2];
    #pragma unroll
    for (int kk = 0; kk < 2; ++kk) {
      const int f0 = kk*32 + g*8;
      float4 a0 = *(const float4*)(ar_ + f0);
      float4 a1 = *(const float4*)(ar_ + f0 + 4);
      float4 c0 = *(const float4*)(colsum + b*128 + f0);
      float4 c1 = *(const float4*)(colsum + b*128 + f0 + 4);
      float4 d0 = *(const float4*)(colsum + b*128 + 64 + f0);
      float4 d1 = *(const float4*)(colsum + b*128 + 64 + f0 + 4);
      float v[8] = {a0.x,a0.y,a0.z,a0.w,a1.x,a1.y,a1.z,a1.w};
      float c[8] = {c0.x,c0.y,c0.z,c0.w,c1.x,c1.y,c1.z,c1.w};
      float d[8] = {d0.x,d0.y,d0.z,d0.w,d1.x,d1.y,d1.z,d1.w};
      #pragma unroll
      for (int j = 0; j < 8; ++j) {
        x0[kk][j] = (short)f2bf(v[j] * __builtin_amdgcn_rcpf(fmaxf(c[j], 1e-12f)));
        x1[kk][j] = (short)f2bf(v[j] * __builtin_amdgcn_rcpf(fmaxf(d[j], 1e-12f)));
      }
    }
    f32x4 p0[4], p1[4];
    #pragma unroll
    for (int t = 0; t < 4; ++t) {
      p0[t][0]=bias[t]; p0[t][1]=bias[t]; p0[t][2]=bias[t]; p0[t][3]=bias[t];
      p1[t][0]=0.f; p1[t][1]=0.f; p1[t][2]=0.f; p1[t][3]=0.f;
      p0[t] = __builtin_amdgcn_mfma_f32_16x16x32_bf16(x0[0], wt[t][0], p0[t], 0,0,0);
      p0[t] = __builtin_amdgcn_mfma_f32_16x16x32_bf16(x0[1], wt[t][1], p0[t], 0,0,0);
      p1[t] = __builtin_amdgcn_mfma_f32_16x16x32_bf16(x1[0], wb[t][0], p1[t], 0,0,0);
      p1[t] = __builtin_amdgcn_mfma_f32_16x16x32_bf16(x1[1], wb[t][1], p1[t], 0,0,0);
    }
    #pragma unroll
    for (int t = 0; t < 4; ++t)
      #pragma unroll
      for (int r = 0; r < 4; ++r) {
        P0[(size_t)(n0 + g*4 + r)*64 + t*16 + er] = p0[t][r];
        P1[(size_t)(n0 + g*4 + r)*64 + t*16 + er] = p1[t][r];
      }
  }
}

// ---------------- per-edge via MFMA, XCD-pinned per batch ----------------
__global__ __launch_bounds__(256) void k_edge_mfma(
    const float* __restrict__ bond, const int* __restrict__ tup,
    const float* __restrict__ P0, const float* __restrict__ P1,
    const float* __restrict__ We, const float* __restrict__ be,
    float* __restrict__ outB)
{
  const int l  = threadIdx.x & 63;
  const int er = l & 15;
  const int g  = l >> 4;
  bf16x8 wh[4][2], wl[4][2];
  #pragma unroll
  for (int t = 0; t < 4; ++t) {
    const int col = t*16 + er;
    #pragma unroll
    for (int kk = 0; kk < 2; ++kk)
      #pragma unroll
      for (int j = 0; j < 8; ++j) {
        const int k = kk*32 + g*8 + j;
        float w = We[k*64 + col];
        unsigned short h = f2bf(w);
        wh[t][kk][j] = (short)h;
        wl[t][kk][j] = (short)f2bf(w - bf2f(h));
      }
  }
  float bias[4];
  #pragma unroll
  for (int t = 0; t < 4; ++t) bias[t] = be[t*16 + er];

  // XCD swizzle: batch b -> XCD pair {2b,2b+1}; P0/P1 of one batch (2 MB)
  // stay resident in that XCD's 4 MiB L2.
  const int b      = (blockIdx.x & 7) >> 1;
  const int within = ((blockIdx.x & 1) << 8) + (blockIdx.x >> 3);   // [0,512)
  const int wib    = within*4 + (threadIdx.x >> 6);                 // [0,2048)

  const float* P0b = P0 + ((size_t)b << 12)*64;
  const float* P1b = P1 + ((size_t)b << 12)*64;

  #pragma unroll 1
  for (int k = 0; k < 4; ++k) {
    const int tile = (b << 13) + wib + (k << 11);
    const int e0 = tile*16;
    const int e  = e0 + er;
    int2 tt = *(const int2*)(tup + (size_t)e*2);
    const float* p0r = P0b + (size_t)tt.x*64;
    const float* p1r = P1b + (size_t)tt.y*64;
    const float* br  = bond + (size_t)e*64;

    bf16x8 ah[2], al[2];
    #pragma unroll
    for (int kk = 0; kk < 2; ++kk) {
      const int f0 = kk*32 + g*8;
      float4 b0 = *(const float4*)(br  + f0);
      float4 b1 = *(const float4*)(br  + f0 + 4);
      float4 q0 = *(const float4*)(p0r + f0);
      float4 q1 = *(const float4*)(p0r + f0 + 4);
      float4 r0 = *(const float4*)(p1r + f0);
      float4 r1 = *(const float4*)(p1r + f0 + 4);
      float v[8];
      v[0] = b0.x + tanh_fast(q0.x + r0.x);
      v[1] = b0.y + tanh_fast(q0.y + r0.y);
      v[2] = b0.z + tanh_fast(q0.z + r0.z);
      v[3] = b0.w + tanh_fast(q0.w + r0.w);
      v[4] = b1.x + tanh_fast(q1.x + r1.x);
      v[5] = b1.y + tanh_fast(q1.y + r1.y);
      v[6] = b1.z + tanh_fast(q1.z + r1.z);
      v[7] = b1.w + tanh_fast(q1.w + r1.w);
      #pragma unroll
      for (int j = 0; j < 8; ++j) {
        unsigned short h = f2bf(v[j]);
        ah[kk][j] = (short)h;
        al[kk][j] = (short)f2bf(v[j] - bf2f(h));
      }
    }

    f32x4 acc[4];
    #pragma unroll
    for (int t = 0; t < 4; ++t) {
      acc[t][0]=bias[t]; acc[t][1]=bias[t]; acc[t][2]=bias[t]; acc[t][3]=bias[t];
      acc[t] = __builtin_amdgcn_mfma_f32_16x16x32_bf16(ah[0], wh[t][0], acc[t], 0,0,0);
      acc[t] = __builtin_amdgcn_mfma_f32_16x16x32_bf16(ah[1], wh[t][1], acc[t], 0,0,0);
      acc[t] = __builtin_amdgcn_mfma_f32_16x16x32_bf16(al[0], wh[t][0], acc[t], 0,0,0);
      acc[t] = __builtin_amdgcn_mfma_f32_16x16x32_bf16(al[1], wh[t][1], acc[t], 0,0,0);
      acc[t] = __builtin_amdgcn_mfma_f32_16x16x32_bf16(ah[0], wl[t][0], acc[t], 0,0,0);
      acc[t] = __builtin_amdgcn_mfma_f32_16x16x32_bf16(ah[1], wl[t][1], acc[t], 0,0,0);
    }

    float* orow = outB + (size_t)e0*64;
    #pragma unroll
    for (int t = 0; t < 4; ++t)
      #pragma unroll
      for (int r = 0; r < 4; ++r)
        orow[(size_t)(g*4 + r)*64 + t*16 + er] = acc[t][r];
  }
}

extern "C" void kernel_launch(void* const* d_in, const int* in_sizes, int n_in,
                              void* d_out, int out_size, void* d_ws, size_t ws_size,
                              hipStream_t stream)
{
  (void)in_sizes; (void)n_in; (void)out_size; (void)ws_size;
  const float* atom = (const float*)d_in[0];
  const float* bond = (const float*)d_in[1];
  const int*   adj  = (const int*)d_in[2];
  const int*   tup  = (const int*)d_in[3];
  const float* Wn   = (const float*)d_in[4];
  const float* We   = (const float*)d_in[5];
  const float* Wn2e = (const float*)d_in[6];
  const float* bn   = (const float*)d_in[7];
  const float* be   = (const float*)d_in[8];
  const float* bn2e = (const float*)d_in[9];

  float* au   = (float*)d_out;             // output 0: (B,N,64)
  float* outB = (float*)d_out + AU_SIZE;   // output 1: (B,N,M,64)

  char* ws = (char*)d_ws;
  int*   cnt    = (int*)ws;                             // 128 KB
  float* colsum = (float*)(ws + 2*NNODE*sizeof(int));   // 2 KB
  float* ar     = (float*)(ws + (size_t)(1<<20));       // 4 MB
  float* pre    = (float*)(ws + (size_t)(6<<20));       // 4 MB
  float* P0     = (float*)(ws + (size_t)(6<<20));       // aliases pre (serial stream)
  float* P1     = (float*)(ws + (size_t)(1<<20));       // aliases ar  (serial stream)

  hipMemsetAsync(d_ws, 0, 2*NNODE*sizeof(int) + BB*128*sizeof(float), stream);

  hipLaunchKernelGGL(k_root,      dim3(AU_SIZE/4/256), dim3(256), 0, stream, atom, ar);
  hipLaunchKernelGGL(k_pre,       dim3(4096),          dim3(256), 0, stream, ar, bond, adj, pre);
  hipLaunchKernelGGL(k_au,        dim3(256),           dim3(256), 0, stream, pre, Wn, bn, au);
  hipLaunchKernelGGL(k_hist,      dim3(NEDGE/256),     dim3(256), 0, stream, tup, cnt);
  hipLaunchKernelGGL(k_colsum,    dim3(BB*32),         dim3(128), 0, stream, au, cnt, colsum);
  hipLaunchKernelGGL(k_p01,       dim3(256),           dim3(256), 0, stream, au, colsum, Wn2e, bn2e, P0, P1);
  hipLaunchKernelGGL(k_edge_mfma, dim3(2048),          dim3(256), 0, stream, bond, tup, P0, P1, We, be, outB);
}